// Round 1
// 13235.051 us; speedup vs baseline: 1.2826x; 1.2826x over previous
//
#include <hip/hip_runtime.h>
#include <stdint.h>

#define NP 100000
#define XS 280    // u16 stride of xt/pt rows: 560 B (u32 stride 140), 16B-aligned
#define HSTR 66   // u16 stride of hsb rows: 132 B (u32 stride 33 -> conflict-free)

typedef unsigned short u16;
typedef unsigned int   u32;

__device__ __forceinline__ float bf2f(u16 v) { return __uint_as_float(((u32)v) << 16); }
__device__ __forceinline__ u16 f2bf(float f) {
    u32 x = __float_as_uint(f);
    u32 r = x + 0x7fffu + ((x >> 16) & 1u);
    return (u16)(r >> 16);
}
__device__ __forceinline__ u32 packbf2(float a, float b) {
    return (u32)f2bf(a) | ((u32)f2bf(b) << 16);
}
__device__ __forceinline__ void ld8bf(const u16* p, float* x) {
    uint4 u = *reinterpret_cast<const uint4*>(p);
    x[0] = __uint_as_float(u.x << 16); x[1] = __uint_as_float(u.x & 0xffff0000u);
    x[2] = __uint_as_float(u.y << 16); x[3] = __uint_as_float(u.y & 0xffff0000u);
    x[4] = __uint_as_float(u.z << 16); x[5] = __uint_as_float(u.z & 0xffff0000u);
    x[6] = __uint_as_float(u.w << 16); x[7] = __uint_as_float(u.w & 0xffff0000u);
}
__device__ __forceinline__ void st8bf(u16* p, const float* x) {
    uint4 u;
    u.x = packbf2(x[0], x[1]); u.y = packbf2(x[2], x[3]);
    u.z = packbf2(x[4], x[5]); u.w = packbf2(x[6], x[7]);
    *reinterpret_cast<uint4*>(p) = u;
}

// ---- dtype-dual loaders ----
template<bool F32>
__device__ __forceinline__ void wpair(const void* W, int idx, float& a, float& b) {
    if constexpr (F32) {
        const float* p = (const float*)W + idx; a = p[0]; b = p[1];
    } else {
        u32 q = *reinterpret_cast<const u32*>((const u16*)W + idx);
        a = __uint_as_float(q << 16);
        b = __uint_as_float(q & 0xffff0000u);
    }
}
template<bool F32>
__device__ __forceinline__ void ldx8(const void* p, int i, float* x) {
    if constexpr (F32) {
        const float* q = (const float*)p + i;
        float4 a = *reinterpret_cast<const float4*>(q);
        float4 b = *reinterpret_cast<const float4*>(q + 4);
        x[0]=a.x; x[1]=a.y; x[2]=a.z; x[3]=a.w;
        x[4]=b.x; x[5]=b.y; x[6]=b.z; x[7]=b.w;
    } else {
        ld8bf((const u16*)p + i, x);
    }
}

// ---------------- rows-per-lane 2-layer MLP accumulate ----------------
// 64 rows/block (row = lane); 4 waves split hidden/output columns.
template<int CIN, int H, int COUT, int CW, bool F32, bool GIN>
__device__ __forceinline__ void mlp2(const void* __restrict__ xrow,
                                     const void* __restrict__ W1, const void* __restrict__ b1,
                                     const void* __restrict__ W2,
                                     int waveU, int lane, u16* __restrict__ hsb,
                                     float* __restrict__ acc)
{
    u16* hr = hsb + lane * HSTR;
#pragma unroll 1
    for (int h0 = 0; h0 < H; h0 += 64) {
        float hacc[16];
#pragma unroll
        for (int j = 0; j < 16; j += 2) wpair<F32>(b1, h0 + waveU * 16 + j, hacc[j], hacc[j + 1]);
#pragma unroll 1
        for (int i0 = 0; i0 < CIN; i0 += 8) {
            float x[8];
            if constexpr (GIN) ldx8<F32>(xrow, i0, x);
            else ld8bf((const u16*)xrow + i0, x);
#pragma unroll
            for (int ii = 0; ii < 8; ii++) {
                const int wb = (i0 + ii) * H + h0 + waveU * 16;
#pragma unroll
                for (int j = 0; j < 16; j += 2) {
                    float wa, wbv;
                    wpair<F32>(W1, wb + j, wa, wbv);
                    hacc[j]     = fmaf(x[ii], wa,  hacc[j]);
                    hacc[j + 1] = fmaf(x[ii], wbv, hacc[j + 1]);
                }
            }
        }
        u32* hw = (u32*)(hr + waveU * 16);
#pragma unroll
        for (int j = 0; j < 16; j += 2)
            hw[j >> 1] = packbf2(fmaxf(hacc[j], 0.f), fmaxf(hacc[j + 1], 0.f));
        __syncthreads();
#pragma unroll 1
        for (int i = 0; i < 64; i++) {
            float xv = bf2f(hr[i]);
            const int wb = (h0 + i) * COUT + waveU * CW;
#pragma unroll
            for (int j = 0; j < CW; j += 2) {
                float wa, wbv;
                wpair<F32>(W2, wb + j, wa, wbv);
                acc[j]     = fmaf(xv, wa,  acc[j]);
                acc[j + 1] = fmaf(xv, wbv, acc[j + 1]);
            }
        }
        __syncthreads();
    }
}

// ---------------- LSE stage: geometry encoder + channel-softmax pool ----------------
// Spill-free layout: all 4 waves process the SAME 4 points per pass (16 passes).
// Hidden (64) is computed cooperatively (16 per wave, uniform weight addrs), shared
// via hsb LDS. Each wave owns a 32-channel slice of the 128 encoder outputs (e[32]).
// Channel-softmax max/sum cross waves through a 1KB LDS reduce buffer.
template<bool F32>
__device__ __forceinline__ void stage_phase(
    const void* __restrict__ coords, const int* __restrict__ nidx,
    const void* __restrict__ lW1, const void* __restrict__ lb1,
    const void* __restrict__ lW2, const void* __restrict__ lb2,
    int row0, int waveU, int lane,
    const u16* __restrict__ xt, u16* __restrict__ pt,
    u16* __restrict__ hsb, float* __restrict__ red)
{
    const int k = lane & 15, psub = lane >> 4;
    const int c0 = waveU * 16;   // this wave's hidden chunk
    const int e0 = waveU * 32;   // this wave's encoder-output chunk
    u16* hr = hsb + lane * HSTR; // hsb row for pair (point psub, neighbor k) == lane

#pragma unroll 1
    for (int g = 0; g < 16; g++) {
        const int pp = g * 4 + psub;
        int n = row0 + pp; if (n >= NP) n = NP - 1;

        // feature-half stats (8 channels per k-lane; butterflies over the 16 k-lanes)
        float f8[8];
        ld8bf(xt + pp * XS + k * 8, f8);
        float mf = f8[0];
#pragma unroll
        for (int q = 1; q < 8; q++) mf = fmaxf(mf, f8[q]);
#pragma unroll
        for (int m = 1; m <= 8; m <<= 1) mf = fmaxf(mf, __shfl_xor(mf, m, 16));
        float ef[8], F = 0.f;
#pragma unroll
        for (int q = 0; q < 8; q++) { ef[q] = __expf(f8[q] - mf); F += ef[q]; }
#pragma unroll
        for (int m = 1; m <= 8; m <<= 1) F += __shfl_xor(F, m, 16);

        // geometry 10-vector
        int j = nidx[(size_t)n * 16 + k];
        float ox, oy, oz, nx, ny, nz;
        if constexpr (F32) {
            const float* cf = (const float*)coords;
            ox = cf[n*3+0]; oy = cf[n*3+1]; oz = cf[n*3+2];
            nx = cf[j*3+0]; ny = cf[j*3+1]; nz = cf[j*3+2];
        } else {
            const u16* cb = (const u16*)coords;
            ox = bf2f(cb[n*3+0]); oy = bf2f(cb[n*3+1]); oz = bf2f(cb[n*3+2]);
            nx = bf2f(cb[j*3+0]); ny = bf2f(cb[j*3+1]); nz = bf2f(cb[j*3+2]);
        }
        float rx = ox-nx, ry = oy-ny, rz = oz-nz;
        float dd = sqrtf(rx*rx + ry*ry + rz*rz);
        float v[10] = {ox,oy,oz,nx,ny,nz,rx,ry,rz,dd};

        // layer1: this wave computes hidden[c0..c0+16) for its (k,psub) pair.
        // Weight addresses uniform per wave -> scalar loads. Fully unrolled (static idx).
        {
            float hh[16];
#pragma unroll
            for (int jj = 0; jj < 16; jj += 2) wpair<F32>(lb1, c0 + jj, hh[jj], hh[jj+1]);
#pragma unroll
            for (int i = 0; i < 10; i++) {
#pragma unroll
                for (int jj = 0; jj < 16; jj += 2) {
                    float wa, wb2; wpair<F32>(lW1, i * 64 + c0 + jj, wa, wb2);
                    hh[jj]     = fmaf(v[i], wa,  hh[jj]);
                    hh[jj + 1] = fmaf(v[i], wb2, hh[jj + 1]);
                }
            }
            u32* hw = (u32*)(hr + c0);
#pragma unroll
            for (int jj = 0; jj < 16; jj += 2)
                hw[jj >> 1] = packbf2(fmaxf(hh[jj], 0.f), fmaxf(hh[jj + 1], 0.f));
        }
        __syncthreads();   // S1: hidden complete in hsb

        // layer2: 64 -> 32 (channels e0..e0+32), hidden read back from LDS
        float e[32];
#pragma unroll
        for (int jj = 0; jj < 32; jj += 2) wpair<F32>(lb2, e0 + jj, e[jj], e[jj+1]);
#pragma unroll 1
        for (int i = 0; i < 64; i += 2) {
            u32 hq = *reinterpret_cast<const u32*>(hr + i);
            float x0 = __uint_as_float(hq << 16);
            float x1 = __uint_as_float(hq & 0xffff0000u);
            const int wb0 = i * 128 + e0;
#pragma unroll
            for (int jj = 0; jj < 32; jj += 2) {
                float wa, wb2;
                wpair<F32>(lW2, wb0 + jj, wa, wb2);
                e[jj]     = fmaf(x0, wa,  e[jj]);
                e[jj + 1] = fmaf(x0, wb2, e[jj + 1]);
                wpair<F32>(lW2, wb0 + 128 + jj, wa, wb2);
                e[jj]     = fmaf(x1, wa,  e[jj]);
                e[jj + 1] = fmaf(x1, wb2, e[jj + 1]);
            }
        }

        // softmax over 256 channels: enc chunks split across waves, feature half via emf*F
        float mchunk = mf;
#pragma unroll
        for (int c = 0; c < 32; c++) mchunk = fmaxf(mchunk, e[c]);
        red[waveU * 64 + lane] = mchunk;
        __syncthreads();   // S2
        float mk = fmaxf(fmaxf(red[lane], red[64 + lane]),
                         fmaxf(red[128 + lane], red[192 + lane]));
        __syncthreads();   // S3 (red reads done before re-write)
        float s = 0.f;
#pragma unroll
        for (int c = 0; c < 32; c++) { float t = __expf(e[c] - mk); s += t; e[c] *= t; }
        red[waveU * 64 + lane] = s;
        __syncthreads();   // S4
        float emf = __expf(mf - mk);
        float stot = red[lane] + red[64 + lane] + red[128 + lane] + red[192 + lane] + emf * F;
        float inv = 1.0f / stot;
        float T = emf * inv;
#pragma unroll
        for (int c = 0; c < 32; c++) e[c] *= inv;

        // reduce over k (16-lane butterflies)
#pragma unroll
        for (int m = 1; m <= 8; m <<= 1) {
#pragma unroll
            for (int c = 0; c < 32; c++) e[c] += __shfl_xor(e[c], m, 16);
            T += __shfl_xor(T, m, 16);
        }

        u16* prow = pt + pp * XS;
        if (k == 0) {
#pragma unroll
            for (int c = 0; c < 32; c += 8) st8bf(prow + e0 + c, e + c);
        }
        if (waveU == 0) {
            float pf[8];
#pragma unroll
            for (int q = 0; q < 8; q++) pf[q] = ef[q] * f8[q] * T;
            st8bf(prow + 128 + k * 8, pf);
        }
    }
}

// ---------------- the fused per-point network ----------------
struct WPtrs { const void* p[28]; };

template<bool F32>
__device__ __forceinline__ void run_all(
    const void* __restrict__ coords, const void* __restrict__ feats,
    const int* __restrict__ nidx, const WPtrs& wp, void* __restrict__ outp,
    u16* __restrict__ xt, u16* __restrict__ pt, u16* __restrict__ hsb,
    float* __restrict__ red)
{
    const int waveU = __builtin_amdgcn_readfirstlane((int)(threadIdx.x >> 6));
    const int lane  = threadIdx.x & 63;
    const int row0  = blockIdx.x * 64;
    int rowL = row0 + lane; if (rowL >= NP) rowL = NP - 1;
    const void* frow = F32 ? (const void*)((const float*)feats + (size_t)rowL * 128)
                           : (const void*)((const u16*)feats + (size_t)rowL * 128);

    // phase 1: mlp1 (128 -> 128 -> 128) -> xt[:,0:128)
    {
        float acc[32];
#pragma unroll
        for (int j = 0; j < 32; j += 2) wpair<F32>(wp.p[3], waveU * 32 + j, acc[j], acc[j + 1]);
        mlp2<128,128,128,32,F32,true>(frow, wp.p[0], wp.p[1], wp.p[2], waveU, lane, hsb, acc);
        u16* xr = xt + lane * XS + waveU * 32;
#pragma unroll
        for (int t = 0; t < 32; t += 8) st8bf(xr + t, acc + t);
    }
    __syncthreads();

    // phase 2: lse1 + pool numerators -> pt[:,0:256)
    stage_phase<F32>(coords, nidx, wp.p[12], wp.p[13], wp.p[14], wp.p[15],
                     row0, waveU, lane, xt, pt, hsb, red);
    __syncthreads();

    // phase 3: pool1 mlp (256 -> 256 -> 128) -> xt[:,0:128)
    {
        float acc[32];
#pragma unroll
        for (int j = 0; j < 32; j += 2) wpair<F32>(wp.p[23], waveU * 32 + j, acc[j], acc[j + 1]);
        mlp2<256,256,128,32,F32,false>(pt + lane * XS, wp.p[20], wp.p[21], wp.p[22], waveU, lane, hsb, acc);
        u16* xr = xt + lane * XS + waveU * 32;
#pragma unroll
        for (int t = 0; t < 32; t += 8) st8bf(xr + t, acc + t);
    }
    __syncthreads();

    // phase 4: lse2 -> pt
    stage_phase<F32>(coords, nidx, wp.p[16], wp.p[17], wp.p[18], wp.p[19],
                     row0, waveU, lane, xt, pt, hsb, red);
    __syncthreads();

    // phase 5: pool2 mlp (256 -> 256 -> 256) -> xt[:,0:256)
    {
        float acc[64];
#pragma unroll
        for (int j = 0; j < 64; j += 2) wpair<F32>(wp.p[27], waveU * 64 + j, acc[j], acc[j + 1]);
        mlp2<256,256,256,64,F32,false>(pt + lane * XS, wp.p[24], wp.p[25], wp.p[26], waveU, lane, hsb, acc);
        u16* xr = xt + lane * XS + waveU * 64;
#pragma unroll
        for (int t = 0; t < 64; t += 8) st8bf(xr + t, acc + t);
    }
    __syncthreads();

    // phase 6: leaky(m2(xt) + m3(feats)) -> out
    {
        float acc[128];
#pragma unroll
        for (int j = 0; j < 128; j += 2) {
            float a2a, a2b, a3a, a3b;
            wpair<F32>(wp.p[7],  waveU * 128 + j, a2a, a2b);
            wpair<F32>(wp.p[11], waveU * 128 + j, a3a, a3b);
            acc[j] = a2a + a3a; acc[j + 1] = a2b + a3b;
        }
        mlp2<256,384,512,128,F32,false>(xt + lane * XS, wp.p[4], wp.p[5], wp.p[6], waveU, lane, hsb, acc);
        mlp2<128,256,512,128,F32,true >(frow, wp.p[8], wp.p[9], wp.p[10], waveU, lane, hsb, acc);
        if (row0 + lane < NP) {
            const size_t ob = (size_t)(row0 + lane) * 512 + waveU * 128;
            if constexpr (F32) {
                float* orow = (float*)outp + ob;
#pragma unroll
                for (int j = 0; j < 128; j += 4) {
                    float r[4];
#pragma unroll
                    for (int q = 0; q < 4; q++) { float vv = acc[j + q]; r[q] = vv > 0.f ? vv : 0.01f * vv; }
                    *reinterpret_cast<float4*>(orow + j) = make_float4(r[0], r[1], r[2], r[3]);
                }
            } else {
                u16* orow = (u16*)outp + ob;
#pragma unroll
                for (int j = 0; j < 128; j += 8) {
                    float r[8];
#pragma unroll
                    for (int q = 0; q < 8; q++) { float vv = acc[j + q]; r[q] = vv > 0.f ? vv : 0.01f * vv; }
                    st8bf(orow + j, r);
                }
            }
        }
    }
}

__global__ __launch_bounds__(256, 2) void k_mega(
    const void* __restrict__ coords, const void* __restrict__ feats,
    const int* __restrict__ nidx, WPtrs wp, void* __restrict__ outp)
{
    __shared__ __align__(16) u16 xt[64 * XS];
    __shared__ __align__(16) u16 pt[64 * XS];
    __shared__ __align__(16) u16 hsb[64 * HSTR];
    __shared__ __align__(16) float red[256];   // cross-wave softmax reduce (1KB)
    __shared__ int sflag;

    // per-block dtype detection: bf16-interpret the first 128 u16 of coords.
    if (threadIdx.x == 0) {
        const u16* c16 = (const u16*)coords;
        int bad = 0;
        for (int i = 0; i < 128; i++) {
            u32 e = (c16[i] >> 7) & 0xFFu;
            bad += (e != 0u && (e < 63u || e > 191u)) ? 1 : 0;
        }
        sflag = bad;
    }
    __syncthreads();

    if (sflag) run_all<true >(coords, feats, nidx, wp, outp, xt, pt, hsb, red);
    else       run_all<false>(coords, feats, nidx, wp, outp, xt, pt, hsb, red);
}

// ---------------- host ----------------
extern "C" void kernel_launch(void* const* d_in, const int* in_sizes, int n_in,
                              void* d_out, int out_size, void* d_ws, size_t ws_size,
                              hipStream_t stream)
{
    const void* coords = d_in[0];
    const void* feats  = d_in[1];
    const int*  nidx   = (const int*)d_in[2];

    WPtrs wp;
    for (int i = 0; i < 28; i++) wp.p[i] = d_in[3 + i];
    // p[0..3]=m1, p[4..7]=m2, p[8..11]=m3, p[12..15]=l1, p[16..19]=l2, p[20..23]=p1, p[24..27]=p2

    k_mega<<<(NP + 63) / 64, 256, 0, stream>>>(coords, feats, nidx, wp, d_out);
}

// Round 2
// 13177.541 us; speedup vs baseline: 1.2882x; 1.0044x over previous
//
#include <hip/hip_runtime.h>
#include <stdint.h>

#define NP 100000
#define XS 280    // u16 stride of xt/pt rows: 560 B (u32 stride 140), 16B-aligned
#define HSTR 66   // u16 stride of hsb rows: 132 B (u32 stride 33 -> conflict-free)

typedef unsigned short u16;
typedef unsigned int   u32;

__device__ __forceinline__ float bf2f(u16 v) { return __uint_as_float(((u32)v) << 16); }
__device__ __forceinline__ u16 f2bf(float f) {
    u32 x = __float_as_uint(f);
    u32 r = x + 0x7fffu + ((x >> 16) & 1u);
    return (u16)(r >> 16);
}
__device__ __forceinline__ u32 packbf2(float a, float b) {
    return (u32)f2bf(a) | ((u32)f2bf(b) << 16);
}
__device__ __forceinline__ void ld8bf(const u16* p, float* x) {
    uint4 u = *reinterpret_cast<const uint4*>(p);
    x[0] = __uint_as_float(u.x << 16); x[1] = __uint_as_float(u.x & 0xffff0000u);
    x[2] = __uint_as_float(u.y << 16); x[3] = __uint_as_float(u.y & 0xffff0000u);
    x[4] = __uint_as_float(u.z << 16); x[5] = __uint_as_float(u.z & 0xffff0000u);
    x[6] = __uint_as_float(u.w << 16); x[7] = __uint_as_float(u.w & 0xffff0000u);
}
__device__ __forceinline__ void st8bf(u16* p, const float* x) {
    uint4 u;
    u.x = packbf2(x[0], x[1]); u.y = packbf2(x[2], x[3]);
    u.z = packbf2(x[4], x[5]); u.w = packbf2(x[6], x[7]);
    *reinterpret_cast<uint4*>(p) = u;
}

// ---- dtype-dual loaders ----
template<bool F32>
__device__ __forceinline__ void wpair(const void* W, int idx, float& a, float& b) {
    if constexpr (F32) {
        const float* p = (const float*)W + idx; a = p[0]; b = p[1];
    } else {
        u32 q = *reinterpret_cast<const u32*>((const u16*)W + idx);
        a = __uint_as_float(q << 16);
        b = __uint_as_float(q & 0xffff0000u);
    }
}
template<bool F32>
__device__ __forceinline__ void ldx8(const void* p, int i, float* x) {
    if constexpr (F32) {
        const float* q = (const float*)p + i;
        float4 a = *reinterpret_cast<const float4*>(q);
        float4 b = *reinterpret_cast<const float4*>(q + 4);
        x[0]=a.x; x[1]=a.y; x[2]=a.z; x[3]=a.w;
        x[4]=b.x; x[5]=b.y; x[6]=b.z; x[7]=b.w;
    } else {
        ld8bf((const u16*)p + i, x);
    }
}

// ---------------- rows-per-lane 2-layer MLP accumulate ----------------
// 64 rows/block (row = lane); 4 waves split hidden/output columns.
template<int CIN, int H, int COUT, int CW, bool F32, bool GIN>
__device__ __forceinline__ void mlp2(const void* __restrict__ xrow,
                                     const void* __restrict__ W1, const void* __restrict__ b1,
                                     const void* __restrict__ W2,
                                     int waveU, int lane, u16* __restrict__ hsb,
                                     float* __restrict__ acc)
{
    u16* hr = hsb + lane * HSTR;
#pragma unroll 1
    for (int h0 = 0; h0 < H; h0 += 64) {
        float hacc[16];
#pragma unroll
        for (int j = 0; j < 16; j += 2) wpair<F32>(b1, h0 + waveU * 16 + j, hacc[j], hacc[j + 1]);
#pragma unroll 1
        for (int i0 = 0; i0 < CIN; i0 += 8) {
            float x[8];
            if constexpr (GIN) ldx8<F32>(xrow, i0, x);
            else ld8bf((const u16*)xrow + i0, x);
#pragma unroll
            for (int ii = 0; ii < 8; ii++) {
                const int wb = (i0 + ii) * H + h0 + waveU * 16;
#pragma unroll
                for (int j = 0; j < 16; j += 2) {
                    float wa, wbv;
                    wpair<F32>(W1, wb + j, wa, wbv);
                    hacc[j]     = fmaf(x[ii], wa,  hacc[j]);
                    hacc[j + 1] = fmaf(x[ii], wbv, hacc[j + 1]);
                }
            }
        }
        u32* hw = (u32*)(hr + waveU * 16);
#pragma unroll
        for (int j = 0; j < 16; j += 2)
            hw[j >> 1] = packbf2(fmaxf(hacc[j], 0.f), fmaxf(hacc[j + 1], 0.f));
        __syncthreads();
#pragma unroll 1
        for (int i = 0; i < 64; i++) {
            float xv = bf2f(hr[i]);
            const int wb = (h0 + i) * COUT + waveU * CW;
#pragma unroll
            for (int j = 0; j < CW; j += 2) {
                float wa, wbv;
                wpair<F32>(W2, wb + j, wa, wbv);
                acc[j]     = fmaf(xv, wa,  acc[j]);
                acc[j + 1] = fmaf(xv, wbv, acc[j + 1]);
            }
        }
        __syncthreads();
    }
}

// ---------------- LSE stage: geometry encoder + channel-softmax pool ----------------
// All 4 waves process the SAME 4 points per pass (16 passes).
// Hidden (64) computed cooperatively (16 per wave, uniform weight addrs), shared
// via hsb LDS. Each wave owns a 32-channel slice of the 128 encoder outputs (e[32]).
// Channel-softmax max/sum cross waves through a 1KB LDS reduce buffer.
template<bool F32>
__device__ __forceinline__ void stage_phase(
    const void* __restrict__ coords, const int* __restrict__ nidx,
    const void* __restrict__ lW1, const void* __restrict__ lb1,
    const void* __restrict__ lW2, const void* __restrict__ lb2,
    int row0, int waveU, int lane,
    const u16* __restrict__ xt, u16* __restrict__ pt,
    u16* __restrict__ hsb, float* __restrict__ red)
{
    const int k = lane & 15, psub = lane >> 4;
    const int c0 = waveU * 16;   // this wave's hidden chunk
    const int e0 = waveU * 32;   // this wave's encoder-output chunk
    u16* hr = hsb + lane * HSTR; // hsb row for pair (point psub, neighbor k) == lane

#pragma unroll 1
    for (int g = 0; g < 16; g++) {
        const int pp = g * 4 + psub;
        int n = row0 + pp; if (n >= NP) n = NP - 1;

        // feature-half stats (8 channels per k-lane; butterflies over the 16 k-lanes)
        float f8[8];
        ld8bf(xt + pp * XS + k * 8, f8);
        float mf = f8[0];
#pragma unroll
        for (int q = 1; q < 8; q++) mf = fmaxf(mf, f8[q]);
#pragma unroll
        for (int m = 1; m <= 8; m <<= 1) mf = fmaxf(mf, __shfl_xor(mf, m, 16));
        float ef[8], F = 0.f;
#pragma unroll
        for (int q = 0; q < 8; q++) { ef[q] = __expf(f8[q] - mf); F += ef[q]; }
#pragma unroll
        for (int m = 1; m <= 8; m <<= 1) F += __shfl_xor(F, m, 16);

        // geometry 10-vector
        int j = nidx[(size_t)n * 16 + k];
        float ox, oy, oz, nx, ny, nz;
        if constexpr (F32) {
            const float* cf = (const float*)coords;
            ox = cf[n*3+0]; oy = cf[n*3+1]; oz = cf[n*3+2];
            nx = cf[j*3+0]; ny = cf[j*3+1]; nz = cf[j*3+2];
        } else {
            const u16* cb = (const u16*)coords;
            ox = bf2f(cb[n*3+0]); oy = bf2f(cb[n*3+1]); oz = bf2f(cb[n*3+2]);
            nx = bf2f(cb[j*3+0]); ny = bf2f(cb[j*3+1]); nz = bf2f(cb[j*3+2]);
        }
        float rx = ox-nx, ry = oy-ny, rz = oz-nz;
        float dd = sqrtf(rx*rx + ry*ry + rz*rz);
        float v[10] = {ox,oy,oz,nx,ny,nz,rx,ry,rz,dd};

        // layer1: this wave computes hidden[c0..c0+16) for its (k,psub) pair.
        {
            float hh[16];
#pragma unroll
            for (int jj = 0; jj < 16; jj += 2) wpair<F32>(lb1, c0 + jj, hh[jj], hh[jj+1]);
#pragma unroll
            for (int i = 0; i < 10; i++) {
#pragma unroll
                for (int jj = 0; jj < 16; jj += 2) {
                    float wa, wb2; wpair<F32>(lW1, i * 64 + c0 + jj, wa, wb2);
                    hh[jj]     = fmaf(v[i], wa,  hh[jj]);
                    hh[jj + 1] = fmaf(v[i], wb2, hh[jj + 1]);
                }
            }
            u32* hw = (u32*)(hr + c0);
#pragma unroll
            for (int jj = 0; jj < 16; jj += 2)
                hw[jj >> 1] = packbf2(fmaxf(hh[jj], 0.f), fmaxf(hh[jj + 1], 0.f));
        }
        __syncthreads();   // S1: hidden complete in hsb

        // layer2: 64 -> 32 (channels e0..e0+32), hidden read back from LDS
        float e[32];
#pragma unroll
        for (int jj = 0; jj < 32; jj += 2) wpair<F32>(lb2, e0 + jj, e[jj], e[jj+1]);
#pragma unroll 1
        for (int i = 0; i < 64; i += 2) {
            u32 hq = *reinterpret_cast<const u32*>(hr + i);
            float x0 = __uint_as_float(hq << 16);
            float x1 = __uint_as_float(hq & 0xffff0000u);
            const int wb0 = i * 128 + e0;
#pragma unroll
            for (int jj = 0; jj < 32; jj += 2) {
                float wa, wb2;
                wpair<F32>(lW2, wb0 + jj, wa, wb2);
                e[jj]     = fmaf(x0, wa,  e[jj]);
                e[jj + 1] = fmaf(x0, wb2, e[jj + 1]);
                wpair<F32>(lW2, wb0 + 128 + jj, wa, wb2);
                e[jj]     = fmaf(x1, wa,  e[jj]);
                e[jj + 1] = fmaf(x1, wb2, e[jj + 1]);
            }
        }

        // softmax over 256 channels: enc chunks split across waves, feature half via emf*F
        float mchunk = mf;
#pragma unroll
        for (int c = 0; c < 32; c++) mchunk = fmaxf(mchunk, e[c]);
        red[waveU * 64 + lane] = mchunk;
        __syncthreads();   // S2
        float mk = fmaxf(fmaxf(red[lane], red[64 + lane]),
                         fmaxf(red[128 + lane], red[192 + lane]));
        __syncthreads();   // S3 (red reads done before re-write)
        float s = 0.f;
#pragma unroll
        for (int c = 0; c < 32; c++) { float t = __expf(e[c] - mk); s += t; e[c] *= t; }
        red[waveU * 64 + lane] = s;
        __syncthreads();   // S4
        float emf = __expf(mf - mk);
        float stot = red[lane] + red[64 + lane] + red[128 + lane] + red[192 + lane] + emf * F;
        float inv = 1.0f / stot;
        float T = emf * inv;
#pragma unroll
        for (int c = 0; c < 32; c++) e[c] *= inv;

        // reduce over k (16-lane butterflies)
#pragma unroll
        for (int m = 1; m <= 8; m <<= 1) {
#pragma unroll
            for (int c = 0; c < 32; c++) e[c] += __shfl_xor(e[c], m, 16);
            T += __shfl_xor(T, m, 16);
        }

        u16* prow = pt + pp * XS;
        if (k == 0) {
#pragma unroll
            for (int c = 0; c < 32; c += 8) st8bf(prow + e0 + c, e + c);
        }
        if (waveU == 0) {
            float pf[8];
#pragma unroll
            for (int q = 0; q < 8; q++) pf[q] = ef[q] * f8[q] * T;
            st8bf(prow + 128 + k * 8, pf);
        }
    }
}

// ---------------- the fused per-point network ----------------
struct WPtrs { const void* p[28]; };

template<bool F32>
__device__ __forceinline__ void run_all(
    const void* __restrict__ coords, const void* __restrict__ feats,
    const int* __restrict__ nidx, const WPtrs& wp, void* __restrict__ outp,
    u16* __restrict__ xt, u16* __restrict__ pt, u16* __restrict__ hsb,
    float* __restrict__ red)
{
    const int waveU = __builtin_amdgcn_readfirstlane((int)(threadIdx.x >> 6));
    const int lane  = threadIdx.x & 63;
    const int row0  = blockIdx.x * 64;
    int rowL = row0 + lane; if (rowL >= NP) rowL = NP - 1;
    const void* frow = F32 ? (const void*)((const float*)feats + (size_t)rowL * 128)
                           : (const void*)((const u16*)feats + (size_t)rowL * 128);

    // phase 1: mlp1 (128 -> 128 -> 128) -> xt[:,0:128)
    {
        float acc[32];
#pragma unroll
        for (int j = 0; j < 32; j += 2) wpair<F32>(wp.p[3], waveU * 32 + j, acc[j], acc[j + 1]);
        mlp2<128,128,128,32,F32,true>(frow, wp.p[0], wp.p[1], wp.p[2], waveU, lane, hsb, acc);
        u16* xr = xt + lane * XS + waveU * 32;
#pragma unroll
        for (int t = 0; t < 32; t += 8) st8bf(xr + t, acc + t);
    }
    __syncthreads();

    // phase 2: lse1 + pool numerators -> pt[:,0:256)
    stage_phase<F32>(coords, nidx, wp.p[12], wp.p[13], wp.p[14], wp.p[15],
                     row0, waveU, lane, xt, pt, hsb, red);
    __syncthreads();

    // phase 3: pool1 mlp (256 -> 256 -> 128) -> xt[:,0:128)
    {
        float acc[32];
#pragma unroll
        for (int j = 0; j < 32; j += 2) wpair<F32>(wp.p[23], waveU * 32 + j, acc[j], acc[j + 1]);
        mlp2<256,256,128,32,F32,false>(pt + lane * XS, wp.p[20], wp.p[21], wp.p[22], waveU, lane, hsb, acc);
        u16* xr = xt + lane * XS + waveU * 32;
#pragma unroll
        for (int t = 0; t < 32; t += 8) st8bf(xr + t, acc + t);
    }
    __syncthreads();

    // phase 4: lse2 -> pt
    stage_phase<F32>(coords, nidx, wp.p[16], wp.p[17], wp.p[18], wp.p[19],
                     row0, waveU, lane, xt, pt, hsb, red);
    __syncthreads();

    // phase 5: pool2 mlp (256 -> 256 -> 256) -> xt[:,0:256)
    {
        float acc[64];
#pragma unroll
        for (int j = 0; j < 64; j += 2) wpair<F32>(wp.p[27], waveU * 64 + j, acc[j], acc[j + 1]);
        mlp2<256,256,256,64,F32,false>(pt + lane * XS, wp.p[24], wp.p[25], wp.p[26], waveU, lane, hsb, acc);
        u16* xr = xt + lane * XS + waveU * 64;
#pragma unroll
        for (int t = 0; t < 64; t += 8) st8bf(xr + t, acc + t);
    }
    __syncthreads();

    // phase 6: leaky(m2(xt) + m3(feats)) -> out
    {
        float acc[128];
#pragma unroll
        for (int j = 0; j < 128; j += 2) {
            float a2a, a2b, a3a, a3b;
            wpair<F32>(wp.p[7],  waveU * 128 + j, a2a, a2b);
            wpair<F32>(wp.p[11], waveU * 128 + j, a3a, a3b);
            acc[j] = a2a + a3a; acc[j + 1] = a2b + a3b;
        }
        mlp2<256,384,512,128,F32,false>(xt + lane * XS, wp.p[4], wp.p[5], wp.p[6], waveU, lane, hsb, acc);
        mlp2<128,256,512,128,F32,true >(frow, wp.p[8], wp.p[9], wp.p[10], waveU, lane, hsb, acc);
        if (row0 + lane < NP) {
            const size_t ob = (size_t)(row0 + lane) * 512 + waveU * 128;
            if constexpr (F32) {
                float* orow = (float*)outp + ob;
#pragma unroll
                for (int j = 0; j < 128; j += 4) {
                    float r[4];
#pragma unroll
                    for (int q = 0; q < 4; q++) { float vv = acc[j + q]; r[q] = vv > 0.f ? vv : 0.01f * vv; }
                    *reinterpret_cast<float4*>(orow + j) = make_float4(r[0], r[1], r[2], r[3]);
                }
            } else {
                u16* orow = (u16*)outp + ob;
#pragma unroll
                for (int j = 0; j < 128; j += 8) {
                    float r[8];
#pragma unroll
                    for (int q = 0; q < 8; q++) { float vv = acc[j + q]; r[q] = vv > 0.f ? vv : 0.01f * vv; }
                    st8bf(orow + j, r);
                }
            }
        }
    }
}

// waves_per_eu pinned to (2,2): LDS (81 KB/block) already caps occupancy at
// 2 blocks/CU = 2 waves/SIMD, so a 128-VGPR budget (4 waves/SIMD target) buys
// nothing and forces phase-6 acc[128] to scratch. Budget 512/2 = 256 VGPRs.
__global__ __launch_bounds__(256)
__attribute__((amdgpu_waves_per_eu(2, 2)))
void k_mega(
    const void* __restrict__ coords, const void* __restrict__ feats,
    const int* __restrict__ nidx, WPtrs wp, void* __restrict__ outp)
{
    __shared__ __align__(16) u16 xt[64 * XS];
    __shared__ __align__(16) u16 pt[64 * XS];
    __shared__ __align__(16) u16 hsb[64 * HSTR];
    __shared__ __align__(16) float red[256];   // cross-wave softmax reduce (1KB)
    __shared__ int sflag;

    // per-block dtype detection: bf16-interpret the first 128 u16 of coords.
    if (threadIdx.x == 0) {
        const u16* c16 = (const u16*)coords;
        int bad = 0;
        for (int i = 0; i < 128; i++) {
            u32 e = (c16[i] >> 7) & 0xFFu;
            bad += (e != 0u && (e < 63u || e > 191u)) ? 1 : 0;
        }
        sflag = bad;
    }
    __syncthreads();

    if (sflag) run_all<true >(coords, feats, nidx, wp, outp, xt, pt, hsb, red);
    else       run_all<false>(coords, feats, nidx, wp, outp, xt, pt, hsb, red);
}

// ---------------- host ----------------
extern "C" void kernel_launch(void* const* d_in, const int* in_sizes, int n_in,
                              void* d_out, int out_size, void* d_ws, size_t ws_size,
                              hipStream_t stream)
{
    const void* coords = d_in[0];
    const void* feats  = d_in[1];
    const int*  nidx   = (const int*)d_in[2];

    WPtrs wp;
    for (int i = 0; i < 28; i++) wp.p[i] = d_in[3 + i];
    // p[0..3]=m1, p[4..7]=m2, p[8..11]=m3, p[12..15]=l1, p[16..19]=l2, p[20..23]=p1, p[24..27]=p2

    k_mega<<<(NP + 63) / 64, 256, 0, stream>>>(coords, feats, nidx, wp, d_out);
}